// Round 8
// baseline (324.779 us; speedup 1.0000x reference)
//
#include <hip/hip_runtime.h>
#include <math.h>

// CARAFE upsample: B=8, C=128, H=W=64, S=2, K=5, M=64, n_enc=100 (pad 128)
// NOTE: ~58us of dur_us is harness re-poison fill (256MiB ws @ ~44us) +
// out-buffer poison + input restore inside the timed window — fixed floor.
// R13 = R0 structure with k_main at 512 threads/block (same 512-block grid):
// 2 blocks/CU x 8 waves = 16 waves/CU (2x R0). R6's accidental experiment
// showed k_main is latency-bound with time ~ 1/waves (4 waves -> 110us,
// 88% stall). Phase A: 8 waves x one 16-row MFMA tile. Phase B: oh-split
// keeps VGPR <=128 (launch_bounds(512,4)) — the R5 failure mode guarded.
// Ledger: R1 split +3.3us, R4 merge +12.6us, R5 prefetch +11.5us (VGPR 256).
//  K_prep:     ew->a_prep bf16, cw->cwT, xpad border zeros (tiny)
//  K_comp_pad: x staged to LDS once -> xpad interior bf16 + 1x1 compress
//              -> m_t[b][h][w][mo] bf16. XCD-chunk swizzled.
//  K_main:     bf16 MFMA encoder conv + pixelshuffle + softmax -> LDS wgt
//              -> fused reassembly (25-tap weighted sum) -> out.

typedef __attribute__((ext_vector_type(8))) short short8;
typedef __attribute__((ext_vector_type(4))) float floatx4;
typedef __attribute__((ext_vector_type(2))) float v2f;

__device__ __forceinline__ unsigned short f2bf(float f) {
  union { float f; unsigned int u; } v; v.f = f;
  unsigned int u = v.u + 0x7fffu + ((v.u >> 16) & 1u);  // RNE
  return (unsigned short)(u >> 16);
}
__device__ __forceinline__ void unpack2(unsigned int u, float& lo, float& hi) {
  union { unsigned int u; float f; } a, b;
  a.u = u << 16; b.u = u & 0xffff0000u;
  lo = a.f; hi = b.f;
}
__device__ __forceinline__ v2f unpack2v(unsigned int u) {
  union { unsigned int u; float f; } a, b;
  a.u = u << 16; b.u = u & 0xffff0000u;
  return (v2f){a.f, b.f};
}

// ---------------------------------------------------------------------------
// K_prep: blocks [0,320): a_prep[tap][n][mo] = bf16(ew[n][mo][tap]) (n>=100->0)
//                         cwT[c][mo] = cw[mo][c]
//         blocks [320,832): zero xpad borders (2 planes per block).
// ---------------------------------------------------------------------------
__global__ __launch_bounds__(256) void k_prep(
    const float* __restrict__ ew, const float* __restrict__ cw,
    unsigned short* __restrict__ a_prep, float* __restrict__ cwT,
    unsigned short* __restrict__ xpad) {
  const int blk = blockIdx.x;
  if (blk < 320) {
    int idx = blk * 256 + (int)threadIdx.x;  // [0, 81920)
    if (idx < 9 * 128 * 64) {
      int mo = idx & 63;
      int n = (idx >> 6) & 127;
      int tap = idx >> 13;
      float v = (n < 100) ? ew[(n * 64 + mo) * 9 + tap] : 0.f;
      a_prep[idx] = f2bf(v);
    } else {
      int r = idx - 9 * 128 * 64;  // [0, 8192)
      int c = r >> 6, mo = r & 63;
      cwT[c * 64 + mo] = cw[mo * 128 + c];
    }
  } else {
    int local = blk - 320;  // [0,512): planes 2*local, 2*local+1
    for (int i = threadIdx.x; i < 800; i += 256) {
      int which = (i >= 400);
      int k = i - which * 400;
      unsigned int* pd =
          (unsigned int*)(xpad + (size_t)(local * 2 + which) * 4896);
      int u32idx;
      if (k < 72) {
        u32idx = k;                      // rows 0-1 full
      } else if (k < 144) {
        u32idx = 2376 + (k - 72);        // rows 66-67 full
      } else {
        int j = k - 144;                 // [0,256): rows 2..65, 4 u32 each
        int r = 2 + (j >> 2), s = j & 3;
        u32idx = r * 36 + (s ? 32 + s : 0);  // cols {0,1} / {66..71}
      }
      pd[u32idx] = 0u;
    }
  }
}

// ---------------------------------------------------------------------------
// K_comp_pad: block (b,h) [XCD-chunk swizzled]. 512 x 256.  (unchanged)
// ---------------------------------------------------------------------------
__global__ __launch_bounds__(256) void k_comp_pad(
    const float* __restrict__ x, const float* __restrict__ cwT,
    const float* __restrict__ cb, unsigned short* __restrict__ m_t,
    unsigned short* __restrict__ xpad) {
  __shared__ __align__(16) float xs[128 * 64];  // 32KB; reused as ms after
  const int lb = (((int)blockIdx.x & 7) << 6) | ((int)blockIdx.x >> 3);
  const int b = lb >> 6;
  const int h = lb & 63;
  const int t = (int)threadIdx.x;

  const float* xrow = x + (((size_t)b * 128) * 64 + h) * 64;
  unsigned short* xpd = xpad + (size_t)b * 128 * 4896 + (h + 2) * 72 + 2;
#pragma unroll
  for (int it = 0; it < 32; ++it) {
    int idx = it * 256 + t;
    int c = idx >> 6, w = idx & 63;
    float v = xrow[(size_t)c * 4096 + w];
    xs[idx] = v;
    xpd[(size_t)c * 4896 + w] = f2bf(v);
  }
  __syncthreads();

  const int wv = __builtin_amdgcn_readfirstlane(t >> 6);
  const int lane = t & 63;
  const int mo0 = wv * 16;

  float acc[16];
#pragma unroll
  for (int k = 0; k < 16; ++k) acc[k] = 0.f;

  const float* wp = cwT + mo0;  // wave-uniform -> s_loads

#pragma unroll 4
  for (int c = 0; c < 128; ++c) {
    float xv = xs[c * 64 + lane];
#pragma unroll
    for (int k = 0; k < 16; ++k)
      acc[k] = fmaf(xv, wp[c * 64 + k], acc[k]);
  }

#pragma unroll
  for (int k = 0; k < 16; ++k) acc[k] += cb[mo0 + k];

  __syncthreads();  // all xs reads done; reuse region as ms[64][72]
  unsigned short* ms = (unsigned short*)xs;
#pragma unroll
  for (int k = 0; k < 8; ++k) {
    unsigned int p = ((unsigned int)f2bf(acc[2 * k + 1]) << 16) | f2bf(acc[2 * k]);
    *(unsigned int*)&ms[lane * 72 + mo0 + 2 * k] = p;
  }
  __syncthreads();
#pragma unroll
  for (int rep = 0; rep < 2; ++rep) {
    int idx = t + rep * 256;  // 0..511 -> w = idx>>3 in [0,64)
    uint4 v = *(const uint4*)&ms[(idx >> 3) * 72 + (idx & 7) * 8];
    *(uint4*)&m_t[(size_t)lb * 4096 + idx * 8] = v;
  }
}

// ---------------------------------------------------------------------------
// K_main: 512 threads/block (8 waves), 512 blocks, XCD-chunk swizzled.
// Phase A: wave w owns encoder rows [16w,16w+16): one 16x16 MFMA tile set.
// Softmax/wgt: waves 0-3 (as before); waves 4-7 ride the barriers.
// Phase B: 32 cg-groups x 4ch cover all 128 channels in one pass; oh-split
//          outer loop keeps accB at 32 VGPR (VGPR<=128 for 16 waves/CU).
// LDS union: m_s (27.6KB) / raw (33.8KB) / wgt_s (12.8KB) share one region.
// ---------------------------------------------------------------------------
__global__ __launch_bounds__(512, 4) void k_main(
    const unsigned short* __restrict__ m_t, const unsigned short* __restrict__ a_prep,
    const float* __restrict__ eb, const unsigned short* __restrict__ xpad,
    float* __restrict__ out) {
  __shared__ __align__(16) float raw[128 * 66];   // 33.8KB union
  unsigned short* m_s = (unsigned short*)raw;     // [dh][w][mo pad72] 27.6KB
  unsigned short* wgt_s = (unsigned short*)raw;   // [oh2][kk25][ow128] 12.8KB
  const int lb = (((int)blockIdx.x & 7) << 6) | ((int)blockIdx.x >> 3);
  const int b = lb >> 6;
  const int h = lb & 63;
  const int t = (int)threadIdx.x;

  // ---- Phase A: stage m rows h-1,h,h+1 (1536 uint4, 3 iters @512thr) ----
  for (int idx = t; idx < 3 * 64 * 8; idx += 512) {
    int r = idx >> 9;
    int rem = idx & 511;
    int w = rem >> 3, u = rem & 7;
    int hh = h + r - 1;
    uint4 val = make_uint4(0u, 0u, 0u, 0u);
    if (hh >= 0 && hh < 64)
      val = *(const uint4*)&m_t[(((b * 64 + hh) * 64 + w) * 64) + u * 8];
    *(uint4*)&m_s[(r * 64 + w) * 72 + u * 8] = val;
  }
  __syncthreads();

  const int wave = t >> 6, lane = t & 63;
  const int quad = lane >> 4, col = lane & 15;
  const int nbase = wave * 16;  // 8 waves x 16 rows = 128

  const floatx4 z4 = {0.f, 0.f, 0.f, 0.f};
  floatx4 acc[4];
#pragma unroll
  for (int p = 0; p < 4; ++p) acc[p] = z4;

  const short8 z8 = {0, 0, 0, 0, 0, 0, 0, 0};

#pragma unroll
  for (int tap = 0; tap < 9; ++tap) {
    const int dh = tap / 3, dw = tap % 3;
#pragma unroll
    for (int half = 0; half < 2; ++half) {
      const int mo0 = half * 32;
      short8 a0 = *(const short8*)&a_prep[((tap * 128 + nbase + col) * 64) + mo0 + quad * 8];
#pragma unroll
      for (int p = 0; p < 4; ++p) {
        int wsrc = p * 16 + col + dw - 1;
        int wc = min(max(wsrc, 0), 63);
        short8 bf = *(const short8*)&m_s[(dh * 64 + wc) * 72 + mo0 + quad * 8];
        if (wsrc < 0 || wsrc > 63) bf = z8;
        acc[p] = __builtin_amdgcn_mfma_f32_16x16x32_bf16(a0, bf, acc[p], 0, 0, 0);
      }
    }
  }

  __syncthreads();  // m_s dead; raw takes over the union
#pragma unroll
  for (int p = 0; p < 4; ++p)
#pragma unroll
    for (int r = 0; r < 4; ++r)
      raw[(nbase + quad * 4 + r) * 66 + p * 16 + col] = acc[p][r];
  __syncthreads();

  // softmax over kk (n = kk*4+q), q = wave (waves 0-3 only), px = lane
  const int q = wave & 3;
  float v[25];
  float inv = 0.f;
  if (wave < 4) {
    float mx = -1e30f;
#pragma unroll
    for (int kk = 0; kk < 25; ++kk) {
      v[kk] = raw[(kk * 4 + q) * 66 + lane] + eb[kk * 4 + q];
      mx = fmaxf(mx, v[kk]);
    }
    float s = 0.f;
#pragma unroll
    for (int kk = 0; kk < 25; ++kk) {
      v[kk] = __expf(v[kk] - mx);
      s += v[kk];
    }
    inv = 1.f / s;
  }

  __syncthreads();  // raw reads done; wgt_s takes over the union
  if (wave < 4) {
    const int ohl = q >> 1;
    const int owp = 2 * lane + (q & 1);
#pragma unroll
    for (int kk = 0; kk < 25; ++kk)
      wgt_s[(ohl * 25 + kk) * 128 + owp] = f2bf(v[kk] * inv);
  }
  __syncthreads();

  // ---- Phase B: reassembly, all 128 channels in one pass, oh-split ----
  const int wg = t & 15;
  const int cg = t >> 4;  // [0,32)
  const int w0 = wg * 4;
  const int c0 = cg * 4;
  const unsigned short* xb =
      xpad + ((size_t)(b * 128 + c0) * 4896) + h * 72 + w0;

  for (int oh = 0; oh < 2; ++oh) {
    v2f accB[4][4];  // [ch][k]
#pragma unroll
    for (int ch = 0; ch < 4; ++ch)
#pragma unroll
      for (int k = 0; k < 4; ++k) accB[ch][k] = (v2f){0.f, 0.f};

    for (int i = 0; i < 5; ++i) {
      float xr[4][8];
#pragma unroll
      for (int ch = 0; ch < 4; ++ch) {
        uint4 rawv = *(const uint4*)(xb + ch * 4896 + i * 72);
        unpack2(rawv.x, xr[ch][0], xr[ch][1]);
        unpack2(rawv.y, xr[ch][2], xr[ch][3]);
        unpack2(rawv.z, xr[ch][4], xr[ch][5]);
        unpack2(rawv.w, xr[ch][6], xr[ch][7]);
      }
#pragma unroll
      for (int j = 0; j < 5; ++j) {
        const int ij = i * 5 + j;
        uint4 wr = *(const uint4*)&wgt_s[(oh * 25 + ij) * 128 + w0 * 2];
        v2f wp[4];
        wp[0] = unpack2v(wr.x);
        wp[1] = unpack2v(wr.y);
        wp[2] = unpack2v(wr.z);
        wp[3] = unpack2v(wr.w);
#pragma unroll
        for (int k = 0; k < 4; ++k)
#pragma unroll
          for (int ch = 0; ch < 4; ++ch) {
            float xv = xr[ch][k + j];
            v2f xvv = {xv, xv};
            accB[ch][k] += xvv * wp[k];  // v_pk_fma_f32
          }
      }
    }

#pragma unroll
    for (int ch = 0; ch < 4; ++ch) {
      float* orow =
          out + ((size_t)(b * 128 + c0 + ch) * 128 + (2 * h + oh)) * 128 + w0 * 2;
      float4 f0 = make_float4(accB[ch][0].x, accB[ch][0].y,
                              accB[ch][1].x, accB[ch][1].y);
      float4 f1 = make_float4(accB[ch][2].x, accB[ch][2].y,
                              accB[ch][3].x, accB[ch][3].y);
      *(float4*)orow = f0;
      *(float4*)(orow + 4) = f1;
    }
  }
}

// ---------------------------------------------------------------------------
extern "C" void kernel_launch(void* const* d_in, const int* in_sizes, int n_in,
                              void* d_out, int out_size, void* d_ws, size_t ws_size,
                              hipStream_t stream) {
  (void)in_sizes; (void)n_in; (void)out_size; (void)ws_size;
  const float* x  = (const float*)d_in[0];
  const float* cw = (const float*)d_in[1];
  const float* cb = (const float*)d_in[2];
  const float* ew = (const float*)d_in[3];
  const float* eb = (const float*)d_in[4];
  float* out = (float*)d_out;

  char* wsb = (char*)d_ws;
  unsigned short* m_t    = (unsigned short*)(wsb);               // 4,194,304 B
  unsigned short* a_prep = (unsigned short*)(wsb + 4194304);     //   147,456 B
  unsigned short* xpad   = (unsigned short*)(wsb + 4341760);     // 10,027,008 B
  float*          cwT    = (float*)(wsb + 14368768);             //    32,768 B

  k_prep<<<dim3(832), dim3(256), 0, stream>>>(ew, cw, a_prep, cwT, xpad);
  k_comp_pad<<<dim3(512), dim3(256), 0, stream>>>(x, cwT, cb, m_t, xpad);
  k_main<<<dim3(512), dim3(512), 0, stream>>>(m_t, a_prep, eb, xpad, out);
}

// Round 9
// 218.481 us; speedup vs baseline: 1.4865x; 1.4865x over previous
//
#include <hip/hip_runtime.h>
#include <math.h>

// CARAFE upsample: B=8, C=128, H=W=64, S=2, K=5, M=64, n_enc=100 (pad 128)
// NOTE: ~58us of dur_us is harness re-poison fill (256MiB ws @ ~44us) +
// out-buffer poison + input restore inside the timed window — fixed floor.
// R14 = R7's 512-thread k_main occupancy bet, with the spill bug fixed:
//  - 2-pass softmax (no v[25] live across barriers; wgt_s in its OWN LDS
//    region, 46.6KB total -> 2 blocks/CU = 16 waves/CU). Bit-identical.
//  - launch_bounds(512,2): R7's (512,4) capped VGPR at 64 (CUDA-style
//    blocks-per-CU semantics) -> 550MB scratch spill traffic, 232us k_main.
//  - oh-loop forced no-unroll (accB stays 32 VGPR; R5 lesson).
// Ledger: R0 fused 134.7/135.1 (best); R1 split +3.3; R4 merge +12.6;
// R5 prefetch-unroll +11.5 (VGPR 256); R7 512thr (64 VGPR, spills) +190.
//  K_prep:     ew->a_prep bf16, cw->cwT, xpad border zeros (tiny)
//  K_comp_pad: x staged to LDS once -> xpad interior bf16 + 1x1 compress
//              -> m_t[b][h][w][mo] bf16. XCD-chunk swizzled.
//  K_main:     512thr/8waves: bf16 MFMA encoder conv + pixelshuffle +
//              2-pass softmax -> LDS wgt -> 25-tap reassembly -> out.

typedef __attribute__((ext_vector_type(8))) short short8;
typedef __attribute__((ext_vector_type(4))) float floatx4;
typedef __attribute__((ext_vector_type(2))) float v2f;

__device__ __forceinline__ unsigned short f2bf(float f) {
  union { float f; unsigned int u; } v; v.f = f;
  unsigned int u = v.u + 0x7fffu + ((v.u >> 16) & 1u);  // RNE
  return (unsigned short)(u >> 16);
}
__device__ __forceinline__ void unpack2(unsigned int u, float& lo, float& hi) {
  union { unsigned int u; float f; } a, b;
  a.u = u << 16; b.u = u & 0xffff0000u;
  lo = a.f; hi = b.f;
}
__device__ __forceinline__ v2f unpack2v(unsigned int u) {
  union { unsigned int u; float f; } a, b;
  a.u = u << 16; b.u = u & 0xffff0000u;
  return (v2f){a.f, b.f};
}

// ---------------------------------------------------------------------------
// K_prep: blocks [0,320): a_prep[tap][n][mo] = bf16(ew[n][mo][tap]) (n>=100->0)
//                         cwT[c][mo] = cw[mo][c]
//         blocks [320,832): zero xpad borders (2 planes per block).
// ---------------------------------------------------------------------------
__global__ __launch_bounds__(256) void k_prep(
    const float* __restrict__ ew, const float* __restrict__ cw,
    unsigned short* __restrict__ a_prep, float* __restrict__ cwT,
    unsigned short* __restrict__ xpad) {
  const int blk = blockIdx.x;
  if (blk < 320) {
    int idx = blk * 256 + (int)threadIdx.x;  // [0, 81920)
    if (idx < 9 * 128 * 64) {
      int mo = idx & 63;
      int n = (idx >> 6) & 127;
      int tap = idx >> 13;
      float v = (n < 100) ? ew[(n * 64 + mo) * 9 + tap] : 0.f;
      a_prep[idx] = f2bf(v);
    } else {
      int r = idx - 9 * 128 * 64;  // [0, 8192)
      int c = r >> 6, mo = r & 63;
      cwT[c * 64 + mo] = cw[mo * 128 + c];
    }
  } else {
    int local = blk - 320;  // [0,512): planes 2*local, 2*local+1
    for (int i = threadIdx.x; i < 800; i += 256) {
      int which = (i >= 400);
      int k = i - which * 400;
      unsigned int* pd =
          (unsigned int*)(xpad + (size_t)(local * 2 + which) * 4896);
      int u32idx;
      if (k < 72) {
        u32idx = k;                      // rows 0-1 full
      } else if (k < 144) {
        u32idx = 2376 + (k - 72);        // rows 66-67 full
      } else {
        int j = k - 144;                 // [0,256): rows 2..65, 4 u32 each
        int r = 2 + (j >> 2), s = j & 3;
        u32idx = r * 36 + (s ? 32 + s : 0);  // cols {0,1} / {66..71}
      }
      pd[u32idx] = 0u;
    }
  }
}

// ---------------------------------------------------------------------------
// K_comp_pad: block (b,h) [XCD-chunk swizzled]. 512 x 256.  (unchanged)
// ---------------------------------------------------------------------------
__global__ __launch_bounds__(256) void k_comp_pad(
    const float* __restrict__ x, const float* __restrict__ cwT,
    const float* __restrict__ cb, unsigned short* __restrict__ m_t,
    unsigned short* __restrict__ xpad) {
  __shared__ __align__(16) float xs[128 * 64];  // 32KB; reused as ms after
  const int lb = (((int)blockIdx.x & 7) << 6) | ((int)blockIdx.x >> 3);
  const int b = lb >> 6;
  const int h = lb & 63;
  const int t = (int)threadIdx.x;

  const float* xrow = x + (((size_t)b * 128) * 64 + h) * 64;
  unsigned short* xpd = xpad + (size_t)b * 128 * 4896 + (h + 2) * 72 + 2;
#pragma unroll
  for (int it = 0; it < 32; ++it) {
    int idx = it * 256 + t;
    int c = idx >> 6, w = idx & 63;
    float v = xrow[(size_t)c * 4096 + w];
    xs[idx] = v;
    xpd[(size_t)c * 4896 + w] = f2bf(v);
  }
  __syncthreads();

  const int wv = __builtin_amdgcn_readfirstlane(t >> 6);
  const int lane = t & 63;
  const int mo0 = wv * 16;

  float acc[16];
#pragma unroll
  for (int k = 0; k < 16; ++k) acc[k] = 0.f;

  const float* wp = cwT + mo0;  // wave-uniform -> s_loads

#pragma unroll 4
  for (int c = 0; c < 128; ++c) {
    float xv = xs[c * 64 + lane];
#pragma unroll
    for (int k = 0; k < 16; ++k)
      acc[k] = fmaf(xv, wp[c * 64 + k], acc[k]);
  }

#pragma unroll
  for (int k = 0; k < 16; ++k) acc[k] += cb[mo0 + k];

  __syncthreads();  // all xs reads done; reuse region as ms[64][72]
  unsigned short* ms = (unsigned short*)xs;
#pragma unroll
  for (int k = 0; k < 8; ++k) {
    unsigned int p = ((unsigned int)f2bf(acc[2 * k + 1]) << 16) | f2bf(acc[2 * k]);
    *(unsigned int*)&ms[lane * 72 + mo0 + 2 * k] = p;
  }
  __syncthreads();
#pragma unroll
  for (int rep = 0; rep < 2; ++rep) {
    int idx = t + rep * 256;  // 0..511 -> w = idx>>3 in [0,64)
    uint4 v = *(const uint4*)&ms[(idx >> 3) * 72 + (idx & 7) * 8];
    *(uint4*)&m_t[(size_t)lb * 4096 + idx * 8] = v;
  }
}

// ---------------------------------------------------------------------------
// K_main: 512 threads/block (8 waves), 512 blocks, XCD-chunk swizzled.
// Phase A: wave w owns encoder rows [16w,16w+16): one 16-row MFMA tile set.
// Softmax: waves 0-3, 2-pass over raw (no v[25] across barriers) -> wgt_s
//          (SEPARATE LDS region; raw stays valid during pass 2).
// Phase B: 32 cg-groups x 4ch cover all 128 channels; oh-loop NOT unrolled
//          (accB stays 32 VGPR). Target VGPR <= 128 -> 2 blocks/CU.
// LDS: region1 raw 33.8KB (union m_s 27.6KB) + region2 wgt_s 12.8KB = 46.6KB.
// ---------------------------------------------------------------------------
__global__ __launch_bounds__(512, 2) void k_main(
    const unsigned short* __restrict__ m_t, const unsigned short* __restrict__ a_prep,
    const float* __restrict__ eb, const unsigned short* __restrict__ xpad,
    float* __restrict__ out) {
  __shared__ __align__(16) float raw[128 * 66];            // 33.8KB (m_s union)
  __shared__ __align__(16) unsigned short wgt_s[2 * 25 * 128];  // 12.8KB separate
  unsigned short* m_s = (unsigned short*)raw;              // [dh][w][mo pad72]
  const int lb = (((int)blockIdx.x & 7) << 6) | ((int)blockIdx.x >> 3);
  const int b = lb >> 6;
  const int h = lb & 63;
  const int t = (int)threadIdx.x;

  // ---- Phase A: stage m rows h-1,h,h+1 (1536 uint4, 3 iters @512thr) ----
  for (int idx = t; idx < 3 * 64 * 8; idx += 512) {
    int r = idx >> 9;
    int rem = idx & 511;
    int w = rem >> 3, u = rem & 7;
    int hh = h + r - 1;
    uint4 val = make_uint4(0u, 0u, 0u, 0u);
    if (hh >= 0 && hh < 64)
      val = *(const uint4*)&m_t[(((b * 64 + hh) * 64 + w) * 64) + u * 8];
    *(uint4*)&m_s[(r * 64 + w) * 72 + u * 8] = val;
  }
  __syncthreads();

  const int wave = t >> 6, lane = t & 63;
  const int quad = lane >> 4, col = lane & 15;
  const int nbase = wave * 16;  // 8 waves x 16 rows = 128

  const floatx4 z4 = {0.f, 0.f, 0.f, 0.f};
  floatx4 acc[4];
#pragma unroll
  for (int p = 0; p < 4; ++p) acc[p] = z4;

  const short8 z8 = {0, 0, 0, 0, 0, 0, 0, 0};

#pragma unroll
  for (int tap = 0; tap < 9; ++tap) {
    const int dh = tap / 3, dw = tap % 3;
#pragma unroll
    for (int half = 0; half < 2; ++half) {
      const int mo0 = half * 32;
      short8 a0 = *(const short8*)&a_prep[((tap * 128 + nbase + col) * 64) + mo0 + quad * 8];
#pragma unroll
      for (int p = 0; p < 4; ++p) {
        int wsrc = p * 16 + col + dw - 1;
        int wc = min(max(wsrc, 0), 63);
        short8 bf = *(const short8*)&m_s[(dh * 64 + wc) * 72 + mo0 + quad * 8];
        if (wsrc < 0 || wsrc > 63) bf = z8;
        acc[p] = __builtin_amdgcn_mfma_f32_16x16x32_bf16(a0, bf, acc[p], 0, 0, 0);
      }
    }
  }

  __syncthreads();  // m_s dead; raw takes over the union
#pragma unroll
  for (int p = 0; p < 4; ++p)
#pragma unroll
    for (int r = 0; r < 4; ++r)
      raw[(nbase + quad * 4 + r) * 66 + p * 16 + col] = acc[p][r];
  __syncthreads();

  // ---- 2-pass softmax over kk (n = kk*4+q), waves 0-3, px = lane ----
  // wgt_s is a separate LDS region, so raw stays readable in pass 2.
  if (wave < 4) {
    const int q = wave;
    float mx = -1e30f;
#pragma unroll
    for (int kk = 0; kk < 25; ++kk)
      mx = fmaxf(mx, raw[(kk * 4 + q) * 66 + lane] + eb[kk * 4 + q]);
    float s = 0.f;
#pragma unroll
    for (int kk = 0; kk < 25; ++kk)
      s += __expf(raw[(kk * 4 + q) * 66 + lane] + eb[kk * 4 + q] - mx);
    float inv = 1.f / s;
    const int ohl = q >> 1;
    const int owp = 2 * lane + (q & 1);
#pragma unroll
    for (int kk = 0; kk < 25; ++kk)
      wgt_s[(ohl * 25 + kk) * 128 + owp] =
          f2bf(__expf(raw[(kk * 4 + q) * 66 + lane] + eb[kk * 4 + q] - mx) * inv);
  }
  __syncthreads();

  // ---- Phase B: reassembly, all 128 channels in one pass, oh-split ----
  const int wg = t & 15;
  const int cg = t >> 4;  // [0,32)
  const int w0 = wg * 4;
  const int c0 = cg * 4;
  const unsigned short* xb =
      xpad + ((size_t)(b * 128 + c0) * 4896) + h * 72 + w0;

#pragma unroll 1
  for (int oh = 0; oh < 2; ++oh) {
    v2f accB[4][4];  // [ch][k]
#pragma unroll
    for (int ch = 0; ch < 4; ++ch)
#pragma unroll
      for (int k = 0; k < 4; ++k) accB[ch][k] = (v2f){0.f, 0.f};

    for (int i = 0; i < 5; ++i) {
      float xr[4][8];
#pragma unroll
      for (int ch = 0; ch < 4; ++ch) {
        uint4 rawv = *(const uint4*)(xb + ch * 4896 + i * 72);
        unpack2(rawv.x, xr[ch][0], xr[ch][1]);
        unpack2(rawv.y, xr[ch][2], xr[ch][3]);
        unpack2(rawv.z, xr[ch][4], xr[ch][5]);
        unpack2(rawv.w, xr[ch][6], xr[ch][7]);
      }
#pragma unroll
      for (int j = 0; j < 5; ++j) {
        const int ij = i * 5 + j;
        uint4 wr = *(const uint4*)&wgt_s[(oh * 25 + ij) * 128 + w0 * 2];
        v2f wp[4];
        wp[0] = unpack2v(wr.x);
        wp[1] = unpack2v(wr.y);
        wp[2] = unpack2v(wr.z);
        wp[3] = unpack2v(wr.w);
#pragma unroll
        for (int k = 0; k < 4; ++k)
#pragma unroll
          for (int ch = 0; ch < 4; ++ch) {
            float xv = xr[ch][k + j];
            v2f xvv = {xv, xv};
            accB[ch][k] += xvv * wp[k];  // v_pk_fma_f32
          }
      }
    }

#pragma unroll
    for (int ch = 0; ch < 4; ++ch) {
      float* orow =
          out + ((size_t)(b * 128 + c0 + ch) * 128 + (2 * h + oh)) * 128 + w0 * 2;
      float4 f0 = make_float4(accB[ch][0].x, accB[ch][0].y,
                              accB[ch][1].x, accB[ch][1].y);
      float4 f1 = make_float4(accB[ch][2].x, accB[ch][2].y,
                              accB[ch][3].x, accB[ch][3].y);
      *(float4*)orow = f0;
      *(float4*)(orow + 4) = f1;
    }
  }
}

// ---------------------------------------------------------------------------
extern "C" void kernel_launch(void* const* d_in, const int* in_sizes, int n_in,
                              void* d_out, int out_size, void* d_ws, size_t ws_size,
                              hipStream_t stream) {
  (void)in_sizes; (void)n_in; (void)out_size; (void)ws_size;
  const float* x  = (const float*)d_in[0];
  const float* cw = (const float*)d_in[1];
  const float* cb = (const float*)d_in[2];
  const float* ew = (const float*)d_in[3];
  const float* eb = (const float*)d_in[4];
  float* out = (float*)d_out;

  char* wsb = (char*)d_ws;
  unsigned short* m_t    = (unsigned short*)(wsb);               // 4,194,304 B
  unsigned short* a_prep = (unsigned short*)(wsb + 4194304);     //   147,456 B
  unsigned short* xpad   = (unsigned short*)(wsb + 4341760);     // 10,027,008 B
  float*          cwT    = (float*)(wsb + 14368768);             //    32,768 B

  k_prep<<<dim3(832), dim3(256), 0, stream>>>(ew, cw, a_prep, cwT, xpad);
  k_comp_pad<<<dim3(512), dim3(256), 0, stream>>>(x, cwT, cb, m_t, xpad);
  k_main<<<dim3(512), dim3(512), 0, stream>>>(m_t, a_prep, eb, xpad, out);
}

// Round 10
// 164.283 us; speedup vs baseline: 1.9769x; 1.3299x over previous
//
#include <hip/hip_runtime.h>
#include <math.h>

// CARAFE upsample: B=8, C=128, H=W=64, S=2, K=5, M=64, n_enc=100 (pad 128)
// NOTE: ~58us of dur_us is harness re-poison fill (256MiB ws @ ~44us) +
// out-buffer poison + input restore inside the timed window — fixed floor.
// R15: occupancy for k_main WITHOUT the 512-thread register trap:
//  k_main at 1024 blocks x 256 thr, block=(b,h,chalf). Phase A + softmax
//  duplicated per chalf pair (R0's exact proven code, 4 waves); Phase B
//  register-thinned via runtime ch-pair loop (2ch/iter: ~90 VGPR peak)
//  covering this block's 64 channels. LDS 33.8KB -> 4 blocks/CU; VGPR<=128
//  -> 16 waves/CU (2x R0). Bit-identical FMA order.
// Ledger: R0 fused 134.7/135.1 (best); R1 split +3.3; R4 merge +12.6;
// R5 prefetch-unroll +11.5 (VGPR 256); R7 512thr lb(512,4) VGPR64 spills
// +190; R8 512thr lb(512,2) VGPR128 spills +84. Root cause shared: 512-thr
// variants exceed the VGPR budget 16 waves/CU requires. This round keeps
// 256 thr.
//  K_prep:     ew->a_prep bf16, cw->cwT, xpad border zeros (unchanged)
//  K_comp_pad: x->LDS once -> xpad bf16 + 1x1 compress -> m_t (unchanged)
//  K_main:     encoder MFMA + pixelshuffle + softmax -> LDS wgt -> 25-tap
//              reassembly (this block's chalf only) -> out.

typedef __attribute__((ext_vector_type(8))) short short8;
typedef __attribute__((ext_vector_type(4))) float floatx4;
typedef __attribute__((ext_vector_type(2))) float v2f;

__device__ __forceinline__ unsigned short f2bf(float f) {
  union { float f; unsigned int u; } v; v.f = f;
  unsigned int u = v.u + 0x7fffu + ((v.u >> 16) & 1u);  // RNE
  return (unsigned short)(u >> 16);
}
__device__ __forceinline__ void unpack2(unsigned int u, float& lo, float& hi) {
  union { unsigned int u; float f; } a, b;
  a.u = u << 16; b.u = u & 0xffff0000u;
  lo = a.f; hi = b.f;
}
__device__ __forceinline__ v2f unpack2v(unsigned int u) {
  union { unsigned int u; float f; } a, b;
  a.u = u << 16; b.u = u & 0xffff0000u;
  return (v2f){a.f, b.f};
}

// ---------------------------------------------------------------------------
// K_prep: blocks [0,320): a_prep[tap][n][mo] = bf16(ew[n][mo][tap]) (n>=100->0)
//                         cwT[c][mo] = cw[mo][c]
//         blocks [320,832): zero xpad borders (2 planes per block).
// ---------------------------------------------------------------------------
__global__ __launch_bounds__(256) void k_prep(
    const float* __restrict__ ew, const float* __restrict__ cw,
    unsigned short* __restrict__ a_prep, float* __restrict__ cwT,
    unsigned short* __restrict__ xpad) {
  const int blk = blockIdx.x;
  if (blk < 320) {
    int idx = blk * 256 + (int)threadIdx.x;  // [0, 81920)
    if (idx < 9 * 128 * 64) {
      int mo = idx & 63;
      int n = (idx >> 6) & 127;
      int tap = idx >> 13;
      float v = (n < 100) ? ew[(n * 64 + mo) * 9 + tap] : 0.f;
      a_prep[idx] = f2bf(v);
    } else {
      int r = idx - 9 * 128 * 64;  // [0, 8192)
      int c = r >> 6, mo = r & 63;
      cwT[c * 64 + mo] = cw[mo * 128 + c];
    }
  } else {
    int local = blk - 320;  // [0,512): planes 2*local, 2*local+1
    for (int i = threadIdx.x; i < 800; i += 256) {
      int which = (i >= 400);
      int k = i - which * 400;
      unsigned int* pd =
          (unsigned int*)(xpad + (size_t)(local * 2 + which) * 4896);
      int u32idx;
      if (k < 72) {
        u32idx = k;                      // rows 0-1 full
      } else if (k < 144) {
        u32idx = 2376 + (k - 72);        // rows 66-67 full
      } else {
        int j = k - 144;                 // [0,256): rows 2..65, 4 u32 each
        int r = 2 + (j >> 2), s = j & 3;
        u32idx = r * 36 + (s ? 32 + s : 0);  // cols {0,1} / {66..71}
      }
      pd[u32idx] = 0u;
    }
  }
}

// ---------------------------------------------------------------------------
// K_comp_pad: block (b,h) [XCD-chunk swizzled]. 512 x 256.  (unchanged)
// ---------------------------------------------------------------------------
__global__ __launch_bounds__(256) void k_comp_pad(
    const float* __restrict__ x, const float* __restrict__ cwT,
    const float* __restrict__ cb, unsigned short* __restrict__ m_t,
    unsigned short* __restrict__ xpad) {
  __shared__ __align__(16) float xs[128 * 64];  // 32KB; reused as ms after
  const int lb = (((int)blockIdx.x & 7) << 6) | ((int)blockIdx.x >> 3);
  const int b = lb >> 6;
  const int h = lb & 63;
  const int t = (int)threadIdx.x;

  const float* xrow = x + (((size_t)b * 128) * 64 + h) * 64;
  unsigned short* xpd = xpad + (size_t)b * 128 * 4896 + (h + 2) * 72 + 2;
#pragma unroll
  for (int it = 0; it < 32; ++it) {
    int idx = it * 256 + t;
    int c = idx >> 6, w = idx & 63;
    float v = xrow[(size_t)c * 4096 + w];
    xs[idx] = v;
    xpd[(size_t)c * 4896 + w] = f2bf(v);
  }
  __syncthreads();

  const int wv = __builtin_amdgcn_readfirstlane(t >> 6);
  const int lane = t & 63;
  const int mo0 = wv * 16;

  float acc[16];
#pragma unroll
  for (int k = 0; k < 16; ++k) acc[k] = 0.f;

  const float* wp = cwT + mo0;  // wave-uniform -> s_loads

#pragma unroll 4
  for (int c = 0; c < 128; ++c) {
    float xv = xs[c * 64 + lane];
#pragma unroll
    for (int k = 0; k < 16; ++k)
      acc[k] = fmaf(xv, wp[c * 64 + k], acc[k]);
  }

#pragma unroll
  for (int k = 0; k < 16; ++k) acc[k] += cb[mo0 + k];

  __syncthreads();  // all xs reads done; reuse region as ms[64][72]
  unsigned short* ms = (unsigned short*)xs;
#pragma unroll
  for (int k = 0; k < 8; ++k) {
    unsigned int p = ((unsigned int)f2bf(acc[2 * k + 1]) << 16) | f2bf(acc[2 * k]);
    *(unsigned int*)&ms[lane * 72 + mo0 + 2 * k] = p;
  }
  __syncthreads();
#pragma unroll
  for (int rep = 0; rep < 2; ++rep) {
    int idx = t + rep * 256;  // 0..511 -> w = idx>>3 in [0,64)
    uint4 v = *(const uint4*)&ms[(idx >> 3) * 72 + (idx & 7) * 8];
    *(uint4*)&m_t[(size_t)lb * 4096 + idx * 8] = v;
  }
}

// ---------------------------------------------------------------------------
// K_main: 1024 blocks = (b,h,chalf), 256 thr, XCD-chunked (XCD b owns batch
// b; both chalf blocks of an (h) adjacent -> m_t/xpad L2-hot, Phase A redone
// per block — cheap vs the occupancy win: 4 blocks/CU = 16 waves/CU).
// Phase A + softmax: byte-identical to R0 (proven VGPR-safe at 4 waves).
// Phase B: this block's 64 channels via runtime ch-pair loop (2 ch/iter),
// accB[2][2][4] + xr[2][8] keeps peak ~90 VGPR. Same FMA order per output.
// LDS union: m_s (27.6KB) / raw (33.8KB) / wgt_s (12.8KB) share one region.
// ---------------------------------------------------------------------------
__global__ __launch_bounds__(256) void k_main(
    const unsigned short* __restrict__ m_t, const unsigned short* __restrict__ a_prep,
    const float* __restrict__ eb, const unsigned short* __restrict__ xpad,
    float* __restrict__ out) {
  __shared__ __align__(16) float raw[128 * 66];   // 33.8KB union
  unsigned short* m_s = (unsigned short*)raw;     // [dh][w][mo pad72] 27.6KB
  unsigned short* wgt_s = (unsigned short*)raw;   // [oh2][kk25][ow128] 12.8KB
  const int bid = (int)blockIdx.x;
  const int lb = ((bid & 7) << 7) | (bid >> 3);   // 1024-bijective XCD chunk
  const int b = lb >> 7;
  const int rem = lb & 127;
  const int h = rem >> 1;
  const int chalf = rem & 1;
  const int t = (int)threadIdx.x;

  // ---- Phase A: stage m rows h-1,h,h+1 ----
  for (int idx = t; idx < 3 * 64 * 8; idx += 256) {
    int r = idx >> 9;
    int rem2 = idx & 511;
    int w = rem2 >> 3, u = rem2 & 7;
    int hh = h + r - 1;
    uint4 val = make_uint4(0u, 0u, 0u, 0u);
    if (hh >= 0 && hh < 64)
      val = *(const uint4*)&m_t[(((b * 64 + hh) * 64 + w) * 64) + u * 8];
    *(uint4*)&m_s[(r * 64 + w) * 72 + u * 8] = val;
  }
  __syncthreads();

  const int wave = t >> 6, lane = t & 63;
  const int quad = lane >> 4, col = lane & 15;
  const int nbase = wave * 32;

  const floatx4 z4 = {0.f, 0.f, 0.f, 0.f};
  floatx4 acc[2][4];
#pragma unroll
  for (int i = 0; i < 2; ++i)
#pragma unroll
    for (int p = 0; p < 4; ++p) acc[i][p] = z4;

  const short8 z8 = {0, 0, 0, 0, 0, 0, 0, 0};

#pragma unroll
  for (int tap = 0; tap < 9; ++tap) {
    const int dh = tap / 3, dw = tap % 3;
#pragma unroll
    for (int half = 0; half < 2; ++half) {
      const int mo0 = half * 32;
      short8 a0 = *(const short8*)&a_prep[((tap * 128 + nbase + col) * 64) + mo0 + quad * 8];
      short8 a1 = *(const short8*)&a_prep[((tap * 128 + nbase + 16 + col) * 64) + mo0 + quad * 8];
#pragma unroll
      for (int p = 0; p < 4; ++p) {
        int wsrc = p * 16 + col + dw - 1;
        int wc = min(max(wsrc, 0), 63);
        short8 bf = *(const short8*)&m_s[(dh * 64 + wc) * 72 + mo0 + quad * 8];
        if (wsrc < 0 || wsrc > 63) bf = z8;
        acc[0][p] = __builtin_amdgcn_mfma_f32_16x16x32_bf16(a0, bf, acc[0][p], 0, 0, 0);
        acc[1][p] = __builtin_amdgcn_mfma_f32_16x16x32_bf16(a1, bf, acc[1][p], 0, 0, 0);
      }
    }
  }

  __syncthreads();  // m_s dead; raw takes over the union
#pragma unroll
  for (int i = 0; i < 2; ++i)
#pragma unroll
    for (int p = 0; p < 4; ++p)
#pragma unroll
      for (int r = 0; r < 4; ++r)
        raw[(nbase + i * 16 + quad * 4 + r) * 66 + p * 16 + col] = acc[i][p][r];
  __syncthreads();

  // softmax over kk (n = kk*4+q), q = wave, px = lane
  const int q = wave;
  float v[25];
  float mx = -1e30f;
#pragma unroll
  for (int kk = 0; kk < 25; ++kk) {
    v[kk] = raw[(kk * 4 + q) * 66 + lane] + eb[kk * 4 + q];
    mx = fmaxf(mx, v[kk]);
  }
  float s = 0.f;
#pragma unroll
  for (int kk = 0; kk < 25; ++kk) {
    v[kk] = __expf(v[kk] - mx);
    s += v[kk];
  }
  float inv = 1.f / s;

  __syncthreads();  // raw reads done; wgt_s takes over the union
  {
    const int ohl = q >> 1;
    const int owp = 2 * lane + (q & 1);
#pragma unroll
    for (int kk = 0; kk < 25; ++kk)
      wgt_s[(ohl * 25 + kk) * 128 + owp] = f2bf(v[kk] * inv);
  }
  __syncthreads();

  // ---- Phase B: this block's 64 channels, 2 channels per iteration ----
  const int wg = t & 15;
  const int cg = t >> 4;
  const int w0 = wg * 4;

#pragma unroll 1
  for (int chp = 0; chp < 2; ++chp) {
    const int c0 = chalf * 64 + cg * 4 + chp * 2;
    const unsigned short* xb =
        xpad + ((size_t)(b * 128 + c0) * 4896) + h * 72 + w0;

    v2f accB[2][2][4];  // [oh][ch2][k]
#pragma unroll
    for (int oh = 0; oh < 2; ++oh)
#pragma unroll
      for (int ch = 0; ch < 2; ++ch)
#pragma unroll
        for (int k = 0; k < 4; ++k) accB[oh][ch][k] = (v2f){0.f, 0.f};

    for (int i = 0; i < 5; ++i) {
      float xr[2][8];
#pragma unroll
      for (int ch = 0; ch < 2; ++ch) {
        uint4 rawv = *(const uint4*)(xb + ch * 4896 + i * 72);
        unpack2(rawv.x, xr[ch][0], xr[ch][1]);
        unpack2(rawv.y, xr[ch][2], xr[ch][3]);
        unpack2(rawv.z, xr[ch][4], xr[ch][5]);
        unpack2(rawv.w, xr[ch][6], xr[ch][7]);
      }
#pragma unroll
      for (int j = 0; j < 5; ++j) {
        const int ij = i * 5 + j;
#pragma unroll
        for (int oh = 0; oh < 2; ++oh) {
          uint4 wr = *(const uint4*)&wgt_s[(oh * 25 + ij) * 128 + w0 * 2];
          v2f wp[4];
          wp[0] = unpack2v(wr.x);
          wp[1] = unpack2v(wr.y);
          wp[2] = unpack2v(wr.z);
          wp[3] = unpack2v(wr.w);
#pragma unroll
          for (int k = 0; k < 4; ++k)
#pragma unroll
            for (int ch = 0; ch < 2; ++ch) {
              float xv = xr[ch][k + j];
              v2f xvv = {xv, xv};
              accB[oh][ch][k] += xvv * wp[k];  // v_pk_fma_f32
            }
        }
      }
    }

#pragma unroll
    for (int ch = 0; ch < 2; ++ch)
#pragma unroll
      for (int oh = 0; oh < 2; ++oh) {
        float* orow =
            out + ((size_t)(b * 128 + c0 + ch) * 128 + (2 * h + oh)) * 128 + w0 * 2;
        float4 f0 = make_float4(accB[oh][ch][0].x, accB[oh][ch][0].y,
                                accB[oh][ch][1].x, accB[oh][ch][1].y);
        float4 f1 = make_float4(accB[oh][ch][2].x, accB[oh][ch][2].y,
                                accB[oh][ch][3].x, accB[oh][ch][3].y);
        *(float4*)orow = f0;
        *(float4*)(orow + 4) = f1;
      }
  }
}

// ---------------------------------------------------------------------------
extern "C" void kernel_launch(void* const* d_in, const int* in_sizes, int n_in,
                              void* d_out, int out_size, void* d_ws, size_t ws_size,
                              hipStream_t stream) {
  (void)in_sizes; (void)n_in; (void)out_size; (void)ws_size;
  const float* x  = (const float*)d_in[0];
  const float* cw = (const float*)d_in[1];
  const float* cb = (const float*)d_in[2];
  const float* ew = (const float*)d_in[3];
  const float* eb = (const float*)d_in[4];
  float* out = (float*)d_out;

  char* wsb = (char*)d_ws;
  unsigned short* m_t    = (unsigned short*)(wsb);               // 4,194,304 B
  unsigned short* a_prep = (unsigned short*)(wsb + 4194304);     //   147,456 B
  unsigned short* xpad   = (unsigned short*)(wsb + 4341760);     // 10,027,008 B
  float*          cwT    = (float*)(wsb + 14368768);             //    32,768 B

  k_prep<<<dim3(832), dim3(256), 0, stream>>>(ew, cw, a_prep, cwT, xpad);
  k_comp_pad<<<dim3(512), dim3(256), 0, stream>>>(x, cwT, cb, m_t, xpad);
  k_main<<<dim3(1024), dim3(256), 0, stream>>>(m_t, a_prep, eb, xpad, out);
}

// Round 11
// 133.735 us; speedup vs baseline: 2.4285x; 1.2284x over previous
//
#include <hip/hip_runtime.h>
#include <math.h>

// CARAFE upsample: B=8, C=128, H=W=64, S=2, K=5, M=64, n_enc=100 (pad 128)
// FINAL (R16) = byte-exact revert to the session best (R0/R12: 134.7us).
// Fixed floor ~58-65us: harness re-poison fills (256MiB @ ~44us, 76% HBM =
// achievable ceiling) + out poison + input restore in the timed window.
// Ledger of measured perturbations (all regressed):
//   R1  split k_main at wgt boundary          +3.3us  (dispatch cost; 16
//        waves/CU for Phase B gained ~0 -> Phase B not wave-starved)
//   R4  merge prep+compress (2 dispatches)    +12.6us (compress s_load loop)
//   R5  Phase-B prefetch + unroll             +11.5us (VGPR 256, 1 blk/CU)
//   R7  512-thr k_main, lb(512,4)             +190us  (VGPR cap 64 -> 550MB
//        scratch spill traffic)
//   R8  512-thr k_main, lb(512,2), 2-pass SM  +84us   (VGPR cap 128 -> spill)
//   R9  1024-blk (b,h,chalf), thin Phase B    +29.6us (VGPR 240 anyway ->
//        still 8 waves/CU; Phase A doubled)
// Structural constraint: k_main's Phase A + v[25] softmax state needs ~240
// VGPR -> 8 waves/CU max; all state-thinning attempts spill; extra blocks
// duplicate Phase A. k_main is latency-chain-bound at that occupancy; the
// 3-dispatch fused structure below is the measured optimum.
//  K_prep:     ew->a_prep bf16, cw->cwT, xpad border zeros (tiny)
//  K_comp_pad: x staged to LDS once -> xpad interior bf16 + 1x1 compress
//              -> m_t[b][h][w][mo] bf16. XCD-chunk swizzled.
//  K_main:     bf16 MFMA encoder conv + pixelshuffle + softmax -> LDS wgt
//              -> fused reassembly (25-tap weighted sum) -> out.

typedef __attribute__((ext_vector_type(8))) short short8;
typedef __attribute__((ext_vector_type(4))) float floatx4;
typedef __attribute__((ext_vector_type(2))) float v2f;

__device__ __forceinline__ unsigned short f2bf(float f) {
  union { float f; unsigned int u; } v; v.f = f;
  unsigned int u = v.u + 0x7fffu + ((v.u >> 16) & 1u);  // RNE
  return (unsigned short)(u >> 16);
}
__device__ __forceinline__ void unpack2(unsigned int u, float& lo, float& hi) {
  union { unsigned int u; float f; } a, b;
  a.u = u << 16; b.u = u & 0xffff0000u;
  lo = a.f; hi = b.f;
}
__device__ __forceinline__ v2f unpack2v(unsigned int u) {
  union { unsigned int u; float f; } a, b;
  a.u = u << 16; b.u = u & 0xffff0000u;
  return (v2f){a.f, b.f};
}

// ---------------------------------------------------------------------------
// K_prep: blocks [0,320): a_prep[tap][n][mo] = bf16(ew[n][mo][tap]) (n>=100->0)
//                         cwT[c][mo] = cw[mo][c]
//         blocks [320,832): zero xpad borders (2 planes per block).
// ---------------------------------------------------------------------------
__global__ __launch_bounds__(256) void k_prep(
    const float* __restrict__ ew, const float* __restrict__ cw,
    unsigned short* __restrict__ a_prep, float* __restrict__ cwT,
    unsigned short* __restrict__ xpad) {
  const int blk = blockIdx.x;
  if (blk < 320) {
    int idx = blk * 256 + (int)threadIdx.x;  // [0, 81920)
    if (idx < 9 * 128 * 64) {
      int mo = idx & 63;
      int n = (idx >> 6) & 127;
      int tap = idx >> 13;
      float v = (n < 100) ? ew[(n * 64 + mo) * 9 + tap] : 0.f;
      a_prep[idx] = f2bf(v);
    } else {
      int r = idx - 9 * 128 * 64;  // [0, 8192)
      int c = r >> 6, mo = r & 63;
      cwT[c * 64 + mo] = cw[mo * 128 + c];
    }
  } else {
    int local = blk - 320;  // [0,512): planes 2*local, 2*local+1
    for (int i = threadIdx.x; i < 800; i += 256) {
      int which = (i >= 400);
      int k = i - which * 400;
      unsigned int* pd =
          (unsigned int*)(xpad + (size_t)(local * 2 + which) * 4896);
      int u32idx;
      if (k < 72) {
        u32idx = k;                      // rows 0-1 full
      } else if (k < 144) {
        u32idx = 2376 + (k - 72);        // rows 66-67 full
      } else {
        int j = k - 144;                 // [0,256): rows 2..65, 4 u32 each
        int r = 2 + (j >> 2), s = j & 3;
        u32idx = r * 36 + (s ? 32 + s : 0);  // cols {0,1} / {66..71}
      }
      pd[u32idx] = 0u;
    }
  }
}

// ---------------------------------------------------------------------------
// K_comp_pad: block (b,h) [XCD-chunk swizzled]. 512 x 256.
//  Stage x[b,:,h,:] (32KB f32) to LDS once, writing bf16 xpad interior as a
//  side effect. Then 1x1 compress: wave wv owns mo [16wv,16wv+16) via SGPR
//  weights; x broadcast from LDS. Epilogue: LDS transpose -> b128 stores.
// ---------------------------------------------------------------------------
__global__ __launch_bounds__(256) void k_comp_pad(
    const float* __restrict__ x, const float* __restrict__ cwT,
    const float* __restrict__ cb, unsigned short* __restrict__ m_t,
    unsigned short* __restrict__ xpad) {
  __shared__ __align__(16) float xs[128 * 64];  // 32KB; reused as ms after
  const int lb = (((int)blockIdx.x & 7) << 6) | ((int)blockIdx.x >> 3);
  const int b = lb >> 6;
  const int h = lb & 63;
  const int t = (int)threadIdx.x;

  const float* xrow = x + (((size_t)b * 128) * 64 + h) * 64;
  unsigned short* xpd = xpad + (size_t)b * 128 * 4896 + (h + 2) * 72 + 2;
#pragma unroll
  for (int it = 0; it < 32; ++it) {
    int idx = it * 256 + t;
    int c = idx >> 6, w = idx & 63;
    float v = xrow[(size_t)c * 4096 + w];
    xs[idx] = v;
    xpd[(size_t)c * 4896 + w] = f2bf(v);
  }
  __syncthreads();

  const int wv = __builtin_amdgcn_readfirstlane(t >> 6);
  const int lane = t & 63;
  const int mo0 = wv * 16;

  float acc[16];
#pragma unroll
  for (int k = 0; k < 16; ++k) acc[k] = 0.f;

  const float* wp = cwT + mo0;  // wave-uniform -> s_loads

#pragma unroll 4
  for (int c = 0; c < 128; ++c) {
    float xv = xs[c * 64 + lane];
#pragma unroll
    for (int k = 0; k < 16; ++k)
      acc[k] = fmaf(xv, wp[c * 64 + k], acc[k]);
  }

#pragma unroll
  for (int k = 0; k < 16; ++k) acc[k] += cb[mo0 + k];

  __syncthreads();  // all xs reads done; reuse region as ms[64][72]
  unsigned short* ms = (unsigned short*)xs;
#pragma unroll
  for (int k = 0; k < 8; ++k) {
    unsigned int p = ((unsigned int)f2bf(acc[2 * k + 1]) << 16) | f2bf(acc[2 * k]);
    *(unsigned int*)&ms[lane * 72 + mo0 + 2 * k] = p;
  }
  __syncthreads();
#pragma unroll
  for (int rep = 0; rep < 2; ++rep) {
    int idx = t + rep * 256;  // 0..511 -> w = idx>>3 in [0,64)
    uint4 v = *(const uint4*)&ms[(idx >> 3) * 72 + (idx & 7) * 8];
    *(uint4*)&m_t[(size_t)lb * 4096 + idx * 8] = v;
  }
}

// ---------------------------------------------------------------------------
// K_main (fused encoder+softmax+reassemble). Block per (b,h), XCD-chunk
// swizzled so XCD b consumes the m_t/xpad its k_comp_pad blocks produced.
// Phase A: bf16 MFMA 3x3 conv (64->128ch), pixelshuffle+softmax -> LDS wgt_s.
// Phase B: out[b][c][2h+oh][ow] = sum_ij xpad[b][c][h+i][w+j]*wgt_s[oh][ij][ow]
// LDS union: m_s (27.6KB) / raw (33.8KB) / wgt_s (12.8KB) share one region.
// ---------------------------------------------------------------------------
__global__ __launch_bounds__(256) void k_main(
    const unsigned short* __restrict__ m_t, const unsigned short* __restrict__ a_prep,
    const float* __restrict__ eb, const unsigned short* __restrict__ xpad,
    float* __restrict__ out) {
  __shared__ __align__(16) float raw[128 * 66];   // 33.8KB union
  unsigned short* m_s = (unsigned short*)raw;     // [dh][w][mo pad72] 27.6KB
  unsigned short* wgt_s = (unsigned short*)raw;   // [oh2][kk25][ow128] 12.8KB
  const int lb = (((int)blockIdx.x & 7) << 6) | ((int)blockIdx.x >> 3);
  const int b = lb >> 6;
  const int h = lb & 63;
  const int t = (int)threadIdx.x;

  // ---- Phase A: stage m rows h-1,h,h+1 ----
  for (int idx = t; idx < 3 * 64 * 8; idx += 256) {
    int r = idx >> 9;
    int rem = idx & 511;
    int w = rem >> 3, u = rem & 7;
    int hh = h + r - 1;
    uint4 val = make_uint4(0u, 0u, 0u, 0u);
    if (hh >= 0 && hh < 64)
      val = *(const uint4*)&m_t[(((b * 64 + hh) * 64 + w) * 64) + u * 8];
    *(uint4*)&m_s[(r * 64 + w) * 72 + u * 8] = val;
  }
  __syncthreads();

  const int wave = t >> 6, lane = t & 63;
  const int quad = lane >> 4, col = lane & 15;
  const int nbase = wave * 32;

  const floatx4 z4 = {0.f, 0.f, 0.f, 0.f};
  floatx4 acc[2][4];
#pragma unroll
  for (int i = 0; i < 2; ++i)
#pragma unroll
    for (int p = 0; p < 4; ++p) acc[i][p] = z4;

  const short8 z8 = {0, 0, 0, 0, 0, 0, 0, 0};

#pragma unroll
  for (int tap = 0; tap < 9; ++tap) {
    const int dh = tap / 3, dw = tap % 3;
#pragma unroll
    for (int half = 0; half < 2; ++half) {
      const int mo0 = half * 32;
      short8 a0 = *(const short8*)&a_prep[((tap * 128 + nbase + col) * 64) + mo0 + quad * 8];
      short8 a1 = *(const short8*)&a_prep[((tap * 128 + nbase + 16 + col) * 64) + mo0 + quad * 8];
#pragma unroll
      for (int p = 0; p < 4; ++p) {
        int wsrc = p * 16 + col + dw - 1;
        int wc = min(max(wsrc, 0), 63);
        short8 bf = *(const short8*)&m_s[(dh * 64 + wc) * 72 + mo0 + quad * 8];
        if (wsrc < 0 || wsrc > 63) bf = z8;
        acc[0][p] = __builtin_amdgcn_mfma_f32_16x16x32_bf16(a0, bf, acc[0][p], 0, 0, 0);
        acc[1][p] = __builtin_amdgcn_mfma_f32_16x16x32_bf16(a1, bf, acc[1][p], 0, 0, 0);
      }
    }
  }

  __syncthreads();  // m_s dead; raw takes over the union
#pragma unroll
  for (int i = 0; i < 2; ++i)
#pragma unroll
    for (int p = 0; p < 4; ++p)
#pragma unroll
      for (int r = 0; r < 4; ++r)
        raw[(nbase + i * 16 + quad * 4 + r) * 66 + p * 16 + col] = acc[i][p][r];
  __syncthreads();

  // softmax over kk (n = kk*4+q), q = wave, px = lane
  const int q = wave;
  float v[25];
  float mx = -1e30f;
#pragma unroll
  for (int kk = 0; kk < 25; ++kk) {
    v[kk] = raw[(kk * 4 + q) * 66 + lane] + eb[kk * 4 + q];
    mx = fmaxf(mx, v[kk]);
  }
  float s = 0.f;
#pragma unroll
  for (int kk = 0; kk < 25; ++kk) {
    v[kk] = __expf(v[kk] - mx);
    s += v[kk];
  }
  float inv = 1.f / s;

  __syncthreads();  // raw reads done; wgt_s takes over the union
  {
    const int ohl = q >> 1;
    const int owp = 2 * lane + (q & 1);
#pragma unroll
    for (int kk = 0; kk < 25; ++kk)
      wgt_s[(ohl * 25 + kk) * 128 + owp] = f2bf(v[kk] * inv);
  }
  __syncthreads();

  // ---- Phase B: reassembly, both channel halves ----
  const int wg = t & 15;
  const int cg = t >> 4;
  const int w0 = wg * 4;

  for (int chalf = 0; chalf < 2; ++chalf) {
    const int c0 = chalf * 64 + cg * 4;
    const unsigned short* xb =
        xpad + ((size_t)(b * 128 + c0) * 4896) + h * 72 + w0;

    v2f accB[2][4][4];  // [oh][ch][k]
#pragma unroll
    for (int oh = 0; oh < 2; ++oh)
#pragma unroll
      for (int ch = 0; ch < 4; ++ch)
#pragma unroll
        for (int k = 0; k < 4; ++k) accB[oh][ch][k] = (v2f){0.f, 0.f};

    for (int i = 0; i < 5; ++i) {
      float xr[4][8];
#pragma unroll
      for (int ch = 0; ch < 4; ++ch) {
        uint4 rawv = *(const uint4*)(xb + ch * 4896 + i * 72);
        unpack2(rawv.x, xr[ch][0], xr[ch][1]);
        unpack2(rawv.y, xr[ch][2], xr[ch][3]);
        unpack2(rawv.z, xr[ch][4], xr[ch][5]);
        unpack2(rawv.w, xr[ch][6], xr[ch][7]);
      }
#pragma unroll
      for (int j = 0; j < 5; ++j) {
        const int ij = i * 5 + j;
#pragma unroll
        for (int oh = 0; oh < 2; ++oh) {
          uint4 wr = *(const uint4*)&wgt_s[(oh * 25 + ij) * 128 + w0 * 2];
          v2f wp[4];
          wp[0] = unpack2v(wr.x);
          wp[1] = unpack2v(wr.y);
          wp[2] = unpack2v(wr.z);
          wp[3] = unpack2v(wr.w);
#pragma unroll
          for (int k = 0; k < 4; ++k)
#pragma unroll
            for (int ch = 0; ch < 4; ++ch) {
              float xv = xr[ch][k + j];
              v2f xvv = {xv, xv};
              accB[oh][ch][k] += xvv * wp[k];  // v_pk_fma_f32
            }
        }
      }
    }

#pragma unroll
    for (int ch = 0; ch < 4; ++ch)
#pragma unroll
      for (int oh = 0; oh < 2; ++oh) {
        float* orow =
            out + ((size_t)(b * 128 + c0 + ch) * 128 + (2 * h + oh)) * 128 + w0 * 2;
        float4 f0 = make_float4(accB[oh][ch][0].x, accB[oh][ch][0].y,
                                accB[oh][ch][1].x, accB[oh][ch][1].y);
        float4 f1 = make_float4(accB[oh][ch][2].x, accB[oh][ch][2].y,
                                accB[oh][ch][3].x, accB[oh][ch][3].y);
        *(float4*)orow = f0;
        *(float4*)(orow + 4) = f1;
      }
  }
}

// ---------------------------------------------------------------------------
extern "C" void kernel_launch(void* const* d_in, const int* in_sizes, int n_in,
                              void* d_out, int out_size, void* d_ws, size_t ws_size,
                              hipStream_t stream) {
  (void)in_sizes; (void)n_in; (void)out_size; (void)ws_size;
  const float* x  = (const float*)d_in[0];
  const float* cw = (const float*)d_in[1];
  const float* cb = (const float*)d_in[2];
  const float* ew = (const float*)d_in[3];
  const float* eb = (const float*)d_in[4];
  float* out = (float*)d_out;

  char* wsb = (char*)d_ws;
  unsigned short* m_t    = (unsigned short*)(wsb);               // 4,194,304 B
  unsigned short* a_prep = (unsigned short*)(wsb + 4194304);     //   147,456 B
  unsigned short* xpad   = (unsigned short*)(wsb + 4341760);     // 10,027,008 B
  float*          cwT    = (float*)(wsb + 14368768);             //    32,768 B

  k_prep<<<dim3(832), dim3(256), 0, stream>>>(ew, cw, a_prep, cwT, xpad);
  k_comp_pad<<<dim3(512), dim3(256), 0, stream>>>(x, cwT, cb, m_t, xpad);
  k_main<<<dim3(512), dim3(256), 0, stream>>>(m_t, a_prep, eb, xpad, out);
}